// Round 1
// baseline (530.567 us; speedup 1.0000x reference)
//
#include <hip/hip_runtime.h>
#include <math.h>

// Problem constants (reference: N=524288, F=128, C=32, EPS=10.0)
#define NS 524288
#define FDIM 128
#define CDIM 32
#define EPSV 10.0f

typedef float v2f __attribute__((ext_vector_type(2)));

// ws layout (floats):
//   [0, 8192)    : v2f AB[c][f] = (a, -b), a = 1/(2*sig^2), b = mean/sig^2
//   [8192, 8224) : d[c] = sum_f mean^2 * a
//   [8224, 8256) : L[c] = sum_f log(sig)
#define WS_D 8192
#define WS_L 8224

__global__ void precomp_kernel(const float* __restrict__ mean,
                               const float* __restrict__ sigma,
                               float* __restrict__ ws) {
    int c = blockIdx.x;   // 32 blocks
    int f = threadIdx.x;  // 128 threads
    float sg  = sigma[c * FDIM + f] + EPSV;
    float m   = mean[c * FDIM + f];
    float inv = 1.0f / (sg * sg);
    float a   = 0.5f * inv;
    float b   = m * inv;
    v2f ab; ab.x = a; ab.y = -b;
    ((v2f*)ws)[c * FDIM + f] = ab;

    float dpart = m * m * a;
    float lpart = __logf(sg);
    // reduce across 128 threads = 2 waves
    for (int off = 32; off; off >>= 1) {
        dpart += __shfl_down(dpart, off);
        lpart += __shfl_down(lpart, off);
    }
    __shared__ float sd[2], sl[2];
    int wv = f >> 6;
    if ((f & 63) == 0) { sd[wv] = dpart; sl[wv] = lpart; }
    __syncthreads();
    if (f == 0) {
        ws[WS_D + c] = sd[0] + sd[1];
        ws[WS_L + c] = sl[0] + sl[1];
    }
}

__launch_bounds__(256)
__global__ void gmm_main_kernel(const float* __restrict__ ft,
                                const int* __restrict__ ygt,
                                const float* __restrict__ cp,
                                const float* __restrict__ ws,
                                float* __restrict__ out) {
    __shared__ float tile[256 * 33];   // ft rows, +1 pad -> 2-way (free) bank access
    __shared__ float Wp[32 * 33];      // W[ci][c], pad -> bank (ci+c)%32, conflict-free gather
    __shared__ float red[4];

    const int tid = threadIdx.x;
    const long long bs = (long long)blockIdx.x * 256;

    // Build W table in LDS: W[ci][c] = (ci!=c) * exp(L[ci]-L[c]) * p[c]/p[ci]
    for (int idx = tid; idx < 1024; idx += 256) {
        int ci = idx >> 5, o = idx & 31;
        float w = 0.0f;
        if (ci != o) {
            float Lci = ws[WS_L + ci];
            float Lo  = ws[WS_L + o];
            w = __expf(Lci - Lo) * cp[o] / cp[ci];
        }
        Wp[ci * 33 + o] = w;
    }

    v2f acc[CDIM];
    #pragma unroll
    for (int c = 0; c < CDIM; ++c) { acc[c].x = 0.0f; acc[c].y = 0.0f; }

    const v2f* __restrict__ AB = (const v2f*)ws;

    for (int ch = 0; ch < 4; ++ch) {
        __syncthreads();  // protect tile from previous chunk's readers (covers Wp on ch=0)
        // Stage: 256 rows x 32 cols of ft, coalesced (8 lanes cover one 128B line)
        {
            const int r0 = tid >> 3, k = tid & 7;
            #pragma unroll
            for (int it = 0; it < 8; ++it) {
                int r = r0 + it * 32;
                const float4 vld = *(const float4*)(ft + (bs + r) * FDIM + ch * 32 + k * 4);
                float* dst = &tile[r * 33 + k * 4];
                dst[0] = vld.x; dst[1] = vld.y; dst[2] = vld.z; dst[3] = vld.w;
            }
        }
        __syncthreads();

        // Load my row's 32 values, build (ft^2, ft) pairs
        v2f v[32];
        #pragma unroll
        for (int f = 0; f < 32; ++f) {
            float t = tile[tid * 33 + f];
            v2f tv; tv.x = t * t; tv.y = t;
            v[f] = tv;
        }

        // acc[c] += (ft^2, ft) . (a, -b)  -> v_pk_fma_f32; AB reads are wave-uniform -> s_load
        #pragma unroll
        for (int c = 0; c < CDIM; ++c) {
            v2f s = acc[c];
            const v2f* __restrict__ abc = AB + c * FDIM + ch * 32;
            #pragma unroll
            for (int f = 0; f < 32; ++f) {
                s = abc[f] * v[f] + s;
            }
            acc[c] = s;
        }
    }

    // Epilogue: quad[c] = acc.x + acc.y + d[c];  logE = -quad
    // out_i = sum_c exp(quad[ci] - quad[c]) * W[ci][c]
    const int ci = ygt[bs + tid];
    float q[CDIM];
    float qb = 0.0f;
    #pragma unroll
    for (int c = 0; c < CDIM; ++c) {
        float qq = acc[c].x + acc[c].y + ws[WS_D + c];
        q[c] = qq;
        qb = (c == ci) ? qq : qb;   // cndmask select, no dynamic reg indexing
    }
    float outv = 0.0f;
    #pragma unroll
    for (int c = 0; c < CDIM; ++c) {
        outv += __expf(qb - q[c]) * Wp[ci * 33 + c];
    }
    float val = __logf(1.0f + outv) * (1.0f / (float)NS);

    // wave(64) -> block -> global reduction
    for (int off = 32; off; off >>= 1) val += __shfl_down(val, off);
    if ((tid & 63) == 0) red[tid >> 6] = val;
    __syncthreads();
    if (tid == 0) atomicAdd(out, red[0] + red[1] + red[2] + red[3]);
}

extern "C" void kernel_launch(void* const* d_in, const int* in_sizes, int n_in,
                              void* d_out, int out_size, void* d_ws, size_t ws_size,
                              hipStream_t stream) {
    const float* ft    = (const float*)d_in[0];
    const float* mean  = (const float*)d_in[1];
    const float* sigma = (const float*)d_in[2];
    const float* cp    = (const float*)d_in[3];
    const int*   ygt   = (const int*)d_in[4];
    float* ws = (float*)d_ws;

    hipMemsetAsync(d_out, 0, sizeof(float), stream);
    precomp_kernel<<<32, 128, 0, stream>>>(mean, sigma, ws);
    gmm_main_kernel<<<NS / 256, 256, 0, stream>>>(ft, ygt, cp, ws, (float*)d_out);
}

// Round 2
// 385.163 us; speedup vs baseline: 1.3775x; 1.3775x over previous
//
#include <hip/hip_runtime.h>
#include <hip/hip_bf16.h>
#include <math.h>

// Problem constants: N=524288, F=128, C=32, EPS=10.0
#define NS 524288
#define FDIM 128
#define CDIM 32
#define EPSV 10.0f

typedef __attribute__((ext_vector_type(8))) short short8;
typedef __attribute__((ext_vector_type(16))) float float16v;

// ws layout (float indices):
//   [0, 4096)    : Bpk bf16[32][256]  -- Bpk[c][2f]=bf16(a_cf), Bpk[c][2f+1]=bf16(-b_cf)
//   [4096, 4128) : d[c] = sum_f mean^2 * a
//   [4128, 4160) : L[c] = sum_f log(sig)
#define WS_D 4096
#define WS_L 4128

static __device__ __forceinline__ short f2bf(float x) {
    __hip_bfloat16 h = __float2bfloat16(x);   // RN
    return __builtin_bit_cast(short, h);
}

static __device__ __forceinline__ short8 make_afrag(float4 v) {
    // packed-K interleave: even k -> ft^2 (pairs with a), odd k -> ft (pairs with -b)
    short8 r;
    r[0] = f2bf(v.x * v.x); r[1] = f2bf(v.x);
    r[2] = f2bf(v.y * v.y); r[3] = f2bf(v.y);
    r[4] = f2bf(v.z * v.z); r[5] = f2bf(v.z);
    r[6] = f2bf(v.w * v.w); r[7] = f2bf(v.w);
    return r;
}

__global__ void precomp_kernel(const float* __restrict__ mean,
                               const float* __restrict__ sigma,
                               float* __restrict__ ws) {
    int c = blockIdx.x;   // 32 blocks
    int f = threadIdx.x;  // 128 threads
    float sg  = sigma[c * FDIM + f] + EPSV;
    float m   = mean[c * FDIM + f];
    float inv = 1.0f / (sg * sg);
    float a   = 0.5f * inv;
    float b   = m * inv;
    // pack (bf16(a) low, bf16(-b) high) -> uint at index c*128+f == bf16 elems (2f, 2f+1)
    unsigned ha = (unsigned short)f2bf(a);
    unsigned hb = (unsigned short)f2bf(-b);
    ((unsigned*)ws)[c * FDIM + f] = ha | (hb << 16);

    float dpart = m * m * a;
    float lpart = __logf(sg);
    for (int off = 32; off; off >>= 1) {
        dpart += __shfl_down(dpart, off);
        lpart += __shfl_down(lpart, off);
    }
    __shared__ float sd[2], sl[2];
    int wv = f >> 6;
    if ((f & 63) == 0) { sd[wv] = dpart; sl[wv] = lpart; }
    __syncthreads();
    if (f == 0) {
        ws[WS_D + c] = sd[0] + sd[1];
        ws[WS_L + c] = sl[0] + sl[1];
    }
}

__launch_bounds__(256)
__global__ void gmm_main_kernel(const float* __restrict__ ft,
                                const int* __restrict__ ygt,
                                const float* __restrict__ cp,
                                const float* __restrict__ ws,
                                float* __restrict__ out) {
    __shared__ float Q[256 * 33];   // quad values, stride 33 -> 2-way (free) banks
    __shared__ float Wp[32 * 33];
    __shared__ float red[4];

    const int tid  = threadIdx.x;
    const int lane = tid & 63;
    const int w    = tid >> 6;          // wave 0..3
    const long long bs = (long long)blockIdx.x * 256;

    // W table: W[ci][o] = (ci!=o) * exp(L[ci]-L[o]) * p[o]/p[ci]
    for (int idx = tid; idx < 1024; idx += 256) {
        int ci = idx >> 5, o = idx & 31;
        float v = 0.0f;
        if (ci != o) v = __expf(ws[WS_L + ci] - ws[WS_L + o]) * cp[o] / cp[ci];
        Wp[ci * 33 + o] = v;
    }

    const int m  = lane & 31;   // MFMA row / class col
    const int kg = lane >> 5;   // k half

    float16v acc0 = {};
    float16v acc1 = {};

    // A: per-lane direct global reads. Lane owns row (w*64 + mt*32 + m), reads
    // float4 at f = s*8 + kg*4 each k-step.
    const float* rowp0 = ft + (bs + w * 64 + m) * FDIM + kg * 4;
    const float* rowp1 = rowp0 + 32 * FDIM;
    // B: bf16 frag = Bpk[class m][k = s*16 + kg*8 .. +8]
    const short8* bp = (const short8*)ws + (m * 32 + kg);

    #pragma unroll
    for (int s = 0; s < 16; ++s) {
        float4 v0 = *(const float4*)(rowp0 + s * 8);
        float4 v1 = *(const float4*)(rowp1 + s * 8);
        short8 bfrag = bp[s * 2];
        short8 a0 = make_afrag(v0);
        short8 a1 = make_afrag(v1);
        acc0 = __builtin_amdgcn_mfma_f32_32x32x16_bf16(a0, bfrag, acc0, 0, 0, 0);
        acc1 = __builtin_amdgcn_mfma_f32_32x32x16_bf16(a1, bfrag, acc1, 0, 0, 0);
    }

    // C/D layout (32x32): col = lane&31, row = (reg&3) + 8*(reg>>2) + 4*(lane>>5)
    #pragma unroll
    for (int r = 0; r < 16; ++r) {
        int row = (r & 3) + 8 * (r >> 2) + 4 * kg;
        Q[(w * 64 + row) * 33 + m]      = acc0[r];
        Q[(w * 64 + 32 + row) * 33 + m] = acc1[r];
    }
    __syncthreads();

    // Epilogue: thread t owns sample row t of the block
    const int ci = ygt[bs + tid];
    float q[CDIM];
    float qb = 0.0f;
    #pragma unroll
    for (int c = 0; c < CDIM; ++c) {
        float qq = Q[tid * 33 + c] + ws[WS_D + c];
        q[c] = qq;
        qb = (c == ci) ? qq : qb;
    }
    float outv = 0.0f;
    #pragma unroll
    for (int c = 0; c < CDIM; ++c) {
        outv += __expf(qb - q[c]) * Wp[ci * 33 + c];
    }
    float val = __logf(1.0f + outv) * (1.0f / (float)NS);

    for (int off = 32; off; off >>= 1) val += __shfl_down(val, off);
    if (lane == 0) red[w] = val;
    __syncthreads();
    if (tid == 0) atomicAdd(out, red[0] + red[1] + red[2] + red[3]);
}

extern "C" void kernel_launch(void* const* d_in, const int* in_sizes, int n_in,
                              void* d_out, int out_size, void* d_ws, size_t ws_size,
                              hipStream_t stream) {
    const float* ft    = (const float*)d_in[0];
    const float* mean  = (const float*)d_in[1];
    const float* sigma = (const float*)d_in[2];
    const float* cp    = (const float*)d_in[3];
    const int*   ygt   = (const int*)d_in[4];
    float* ws = (float*)d_ws;

    hipMemsetAsync(d_out, 0, sizeof(float), stream);
    precomp_kernel<<<32, 128, 0, stream>>>(mean, sigma, ws);
    gmm_main_kernel<<<NS / 256, 256, 0, stream>>>(ft, ygt, cp, ws, (float*)d_out);
}